// Round 3
// baseline (17711.780 us; speedup 1.0000x reference)
//
#include <hip/hip_runtime.h>
#include <hip/hip_bf16.h>

__device__ __forceinline__ float sigf(float x) { return 1.0f / (1.0f + __expf(-x)); }

// Literal f32 transcription — ABI bisect round: output now written as f32.
// B=256, T=128, D=64, H=512, 4H=2048. Output (256, 255, 64) f32.
// ws layout (f32 buffers, 3.8 MB total):
#define OFF_XLAST 0u         // 256x64 f32   (64 KB)
#define OFF_XBUF  65536u     // 256x64 f32   (64 KB)  decoder x carry
#define OFF_H1    131072u    // 256x512 f32  (512 KB) encoder L1 h
#define OFF_H     655360u    // 256x512 f32  (512 KB) running h
#define OFF_C     1179648u   // 256x512 f32  (512 KB) running c
#define OFF_Z     1703936u   // 256x2048 f32 (2 MB)   gate pre-activations

__global__ void xlast_k(const float* __restrict__ enc, float* __restrict__ xl) {
    int i = blockIdx.x * 256 + threadIdx.x;        // 16384
    int b = i >> 6, d = i & 63;
    xl[i] = enc[(b * 128 + 127) * 64 + d];         // last timestep only
}

// z[b][n] = bias[n] + sum_k x[b][k] W[k][n]  (+ sum_k h[b][k] U[k][n] if U)
// grid 2048 = 256 b-blocks x 8 n-chunks; n consecutive across threads -> W/U coalesced
__global__ void zker(const float* __restrict__ x, int xd,
                     const float* __restrict__ h,
                     const float* __restrict__ W, const float* __restrict__ U,
                     const float* __restrict__ bias, float* __restrict__ z) {
    int b = blockIdx.x >> 3, nc = blockIdx.x & 7;
    int n = nc * 256 + threadIdx.x;
    float acc = bias[n];
    const float* xr = x + b * xd;
    for (int k = 0; k < xd; ++k) acc = fmaf(xr[k], W[k * 2048 + n], acc);
    if (U != nullptr) {
        const float* hr = h + b * 512;
        for (int k = 0; k < 512; ++k) acc = fmaf(hr[k], U[k * 2048 + n], acc);
    }
    z[b * 2048 + n] = acc;
}

// gate split order per reference: i | f | g | o  (512 each)
// enc:  c = sig(i)*relu(g);            h = sig(o)*relu(c)
// dec:  c = sig(f)*c + sig(i)*relu(g); h = sig(o)*relu(c)
template <bool DEC>
__global__ void gatesk(const float* __restrict__ z, float* __restrict__ c,
                       float* __restrict__ h) {
    int i = blockIdx.x * 256 + threadIdx.x;        // 131072
    int b = i >> 9, j = i & 511;
    const float* zr = z + b * 2048;
    float zi = zr[j], zf = zr[512 + j], zg = zr[1024 + j], zo = zr[1536 + j];
    float ig = sigf(zi) * fmaxf(zg, 0.0f);
    float cv = DEC ? (sigf(zf) * c[i] + ig) : ig;
    c[i] = cv;
    h[i] = sigf(zo) * fmaxf(cv, 0.0f);
}

// y[b][d] = bdense[d] + sum_k h[b][k] Wdense[k][d]; writes out[b][t][d] (f32) and x-carry
__global__ void yker(const float* __restrict__ h, const float* __restrict__ Wd,
                     const float* __restrict__ bd, float* __restrict__ xbuf,
                     float* __restrict__ out, int t) {
    int i = blockIdx.x * 256 + threadIdx.x;        // 16384
    int b = i >> 6, d = i & 63;
    const float* hr = h + b * 512;
    float acc = bd[d];
    for (int k = 0; k < 512; ++k) acc = fmaf(hr[k], Wd[k * 64 + d], acc);
    xbuf[i] = acc;
    out[(b * 255 + t) * 64 + d] = acc;
}

extern "C" void kernel_launch(void* const* d_in, const int* in_sizes, int n_in,
                              void* d_out, int out_size, void* d_ws, size_t ws_size,
                              hipStream_t stream) {
    const float* enc    = (const float*)d_in[0];
    const float* We0    = (const float*)d_in[2];
    const float* be0    = (const float*)d_in[4];
    const float* We1    = (const float*)d_in[5];
    const float* be1    = (const float*)d_in[7];
    const float* Wd0    = (const float*)d_in[8];
    const float* Ud0    = (const float*)d_in[9];
    const float* bd0    = (const float*)d_in[10];
    const float* Wd1    = (const float*)d_in[11];
    const float* Ud1    = (const float*)d_in[12];
    const float* bd1    = (const float*)d_in[13];
    const float* Wdense = (const float*)d_in[14];
    const float* bdense = (const float*)d_in[15];
    float* out = (float*)d_out;
    char* ws  = (char*)d_ws;

    float* xlast = (float*)(ws + OFF_XLAST);
    float* xbuf  = (float*)(ws + OFF_XBUF);
    float* h1    = (float*)(ws + OFF_H1);
    float* hbuf  = (float*)(ws + OFF_H);
    float* cbuf  = (float*)(ws + OFF_C);
    float* zbuf  = (float*)(ws + OFF_Z);

    // ---- encoder (last timestep only; enc_layer has no h/U term) ----
    xlast_k<<<64, 256, 0, stream>>>(enc, xlast);
    zker  <<<2048, 256, 0, stream>>>(xlast, 64, nullptr, We0, nullptr, be0, zbuf);
    gatesk<false><<<512, 256, 0, stream>>>(zbuf, cbuf, h1);
    zker  <<<2048, 256, 0, stream>>>(h1, 512, nullptr, We1, nullptr, be1, zbuf);
    gatesk<false><<<512, 256, 0, stream>>>(zbuf, cbuf, hbuf);   // enc_h, enc_c

    // x0 = enc_h @ Wdense + bdense -> out[:,254,:] (seq[0] after reversal), x carry
    yker<<<64, 256, 0, stream>>>(hbuf, Wdense, bdense, xbuf, out, 254);

    // ---- 254 sequential decoder cells, literal dataflow ----
    for (int k = 0; k < 254; ++k) {
        const float* W = (k & 1) ? Wd1 : Wd0;
        const float* U = (k & 1) ? Ud1 : Ud0;
        const float* b = (k & 1) ? bd1 : bd0;
        zker  <<<2048, 256, 0, stream>>>(xbuf, 64, hbuf, W, U, b, zbuf);
        gatesk<true><<<512, 256, 0, stream>>>(zbuf, cbuf, hbuf);
        // y_k = seq[k+1] -> out[:, 254-(k+1), :], and becomes next x
        yker<<<64, 256, 0, stream>>>(hbuf, Wdense, bdense, xbuf, out, 253 - k);
    }
}

// Round 4
// 4018.058 us; speedup vs baseline: 4.4080x; 4.4080x over previous
//
#include <hip/hip_runtime.h>
#include <hip/hip_bf16.h>
#include <cstdint>

typedef __bf16 bf16x8 __attribute__((ext_vector_type(8)));
typedef float  f32x4  __attribute__((ext_vector_type(4)));
typedef __hip_bfloat16 bf16;

__device__ __forceinline__ float sigmoidf_(float x) { return 1.0f / (1.0f + __expf(-x)); }

// Problem constants: B=256, T=128, D=64, H=512, 4H=2048. Output (256,255,64) f32.
// ws layout (byte offsets, all 256-aligned)
#define OFF_U0      0u           // Ufold0 packed: 2048 x 512 bf16 (2 MB)
#define OFF_U1      2097152u     // Ufold1 packed (2 MB)
#define OFF_WE0PK   4194304u     // We0 packed: 2048 x 64 bf16 (256 KB)
#define OFF_WE1PK   4456448u     // We1 packed: 2048 x 512 bf16 (2 MB)
#define OFF_WDPK    6553600u     // Wdense^T: 64 x 512 bf16 (64 KB)
#define OFF_BE0P    6619136u     // be0 permuted f32 (8 KB)
#define OFF_BE1P    6627328u
#define OFF_B0F     6635520u     // folded dec bias 0 (8 KB)
#define OFF_B1F     6643712u
#define OFF_A0      6651904u     // enc last-step input bf16: 256 x 64 (32 KB)
#define OFF_H1      6684672u     // enc layer1 h bf16: 256 x 512 (256 KB)
#define OFF_C       6946816u     // c state f32: 256 x 512 (512 KB)
#define OFF_HALL    7471104u     // h history bf16: 255 x 256 x 512 (66.8 MB)
#define BH          131072       // elems per h slab (256*512)

// ---- one-time prep kernels ----------------------------------------------

// stored column permutation: np = jt*256 + g*64 + jl  <->  n = g*512 + jt*64 + jl
__global__ void cast_x(const float* __restrict__ enc, bf16* __restrict__ A0) {
    int i = blockIdx.x * 256 + threadIdx.x;           // 16384 total
    int b = i >> 6, d = i & 63;
    A0[i] = __float2bfloat16(enc[(b * 128 + 127) * 64 + d]);
}

__global__ void pack_gatew(const float* __restrict__ W, bf16* __restrict__ out, int K) {
    int np = blockIdx.x;
    int jt = np >> 8, g = (np >> 6) & 3, jl = np & 63;
    int n = g * 512 + jt * 64 + jl;
    for (int k = threadIdx.x; k < K; k += blockDim.x)
        out[np * K + k] = __float2bfloat16(W[k * 2048 + n]);
}

__global__ void pack_wd(const float* __restrict__ Wdense, bf16* __restrict__ out) {
    int d = blockIdx.x;                               // 64
    for (int k = threadIdx.x; k < 512; k += 256)
        out[d * 512 + k] = __float2bfloat16(Wdense[k * 64 + d]);
}

// Ufold[np][hk] = sum_d Wdense[hk][d]*Wd[d][n] + Ud[hk][n]   (bf16 out, packed layout)
__global__ void fold_u(const float* __restrict__ Wdense, const float* __restrict__ Wd,
                       const float* __restrict__ Ud, bf16* __restrict__ out) {
    __shared__ float wcol[64];
    int np = blockIdx.x;
    int jt = np >> 8, g = (np >> 6) & 3, jl = np & 63;
    int n = g * 512 + jt * 64 + jl;
    if (threadIdx.x < 64) wcol[threadIdx.x] = Wd[threadIdx.x * 2048 + n];
    __syncthreads();
    for (int hk = threadIdx.x; hk < 512; hk += 256) {
        float s = Ud[hk * 2048 + n];
        const float* wr = Wdense + hk * 64;
        #pragma unroll
        for (int d = 0; d < 64; ++d) s += wr[d] * wcol[d];
        out[np * 512 + hk] = __float2bfloat16(s);
    }
}

__global__ void prep_bias(const float* __restrict__ be0, const float* __restrict__ be1,
                          const float* __restrict__ bd0, const float* __restrict__ bd1,
                          const float* __restrict__ bdense,
                          const float* __restrict__ Wd0, const float* __restrict__ Wd1,
                          float* __restrict__ be0p, float* __restrict__ be1p,
                          float* __restrict__ b0f, float* __restrict__ b1f) {
    int np = blockIdx.x * blockDim.x + threadIdx.x;
    if (np >= 2048) return;
    int jt = np >> 8, g = (np >> 6) & 3, jl = np & 63;
    int n = g * 512 + jt * 64 + jl;
    be0p[np] = be0[n];
    be1p[np] = be1[n];
    float s0 = bd0[n], s1 = bd1[n];
    for (int d = 0; d < 64; ++d) {
        float bv = bdense[d];
        s0 += bv * Wd0[d * 2048 + n];
        s1 += bv * Wd1[d * 2048 + n];
    }
    b0f[np] = s0;
    b1f[np] = s1;
}

// ---- cell kernel ---------------------------------------------------------
// z = A(256 x KDIM) @ Upk^T + bias, gates i,f,g,o -> update c,h
// grid (8 row-blocks of 32, 8 jt of 64 H-cols); 4 waves, wave w = gate w.
template <int KDIM, bool HAS_CPREV, bool WRITE_C>
__global__ void cell_kernel(const bf16* __restrict__ A, const bf16* __restrict__ Upk,
                            const float* __restrict__ bias, float* __restrict__ cbuf,
                            bf16* __restrict__ hout) {
    __shared__ float zbuf[4][32][65];
    const int tid = threadIdx.x;
    const int w = tid >> 6, lane = tid & 63;
    const int rb = blockIdx.x, jt = blockIdx.y;
    const int row0 = rb * 32;
    const int col0 = jt * 256 + w * 64;               // packed col base (gate w)
    const int lr = lane & 15, lk = (lane >> 4) * 8;

    f32x4 acc[2][4] = {};
    const bf16* Abase = A + (row0 + lr) * KDIM + lk;
    const bf16* Bbase = Upk + (size_t)(col0 + lr) * KDIM + lk;

    #pragma unroll
    for (int kk = 0; kk < KDIM / 32; ++kk) {
        bf16x8 a0 = *reinterpret_cast<const bf16x8*>(Abase + kk * 32);
        bf16x8 a1 = *reinterpret_cast<const bf16x8*>(Abase + 16 * KDIM + kk * 32);
        #pragma unroll
        for (int n = 0; n < 4; ++n) {
            bf16x8 bfr = *reinterpret_cast<const bf16x8*>(Bbase + n * 16 * KDIM + kk * 32);
            acc[0][n] = __builtin_amdgcn_mfma_f32_16x16x32_bf16(a0, bfr, acc[0][n], 0, 0, 0);
            acc[1][n] = __builtin_amdgcn_mfma_f32_16x16x32_bf16(a1, bfr, acc[1][n], 0, 0, 0);
        }
    }
    // D layout: col = lane&15, row = (lane>>4)*4 + reg  [verified m89/m91]
    #pragma unroll
    for (int n = 0; n < 4; ++n) {
        float bv = bias[col0 + n * 16 + lr];
        #pragma unroll
        for (int m = 0; m < 2; ++m)
            #pragma unroll
            for (int r = 0; r < 4; ++r)
                zbuf[w][m * 16 + (lane >> 4) * 4 + r][n * 16 + lr] = acc[m][n][r] + bv;
    }
    __syncthreads();
    #pragma unroll
    for (int e = 0; e < 8; ++e) {
        int idx = e * 256 + tid;
        int r = idx >> 6, jl = idx & 63;
        float zi = zbuf[0][r][jl], zf = zbuf[1][r][jl];
        float zg = zbuf[2][r][jl], zo = zbuf[3][r][jl];
        int b = row0 + r, j = jt * 64 + jl;
        float ig = sigmoidf_(zi) * fmaxf(zg, 0.0f);
        float cv;
        if (HAS_CPREV) cv = sigmoidf_(zf) * cbuf[b * 512 + j] + ig;
        else           cv = ig;
        float h = sigmoidf_(zo) * fmaxf(cv, 0.0f);
        if (WRITE_C) cbuf[b * 512 + j] = cv;
        hout[b * 512 + j] = __float2bfloat16(h);
    }
}

// ---- final Y GEMM: (255*256 x 512) @ Wdense(512 x 64) -> out (f32) reversed ----
__global__ void y_kernel(const bf16* __restrict__ Hall, const bf16* __restrict__ Wdpk,
                         const float* __restrict__ bdense, float* __restrict__ out) {
    const int tid = threadIdx.x, w = tid >> 6, lane = tid & 63;
    const int lr = lane & 15, lk = (lane >> 4) * 8;
    const long row0 = (long)blockIdx.x * 64 + w * 16;
    f32x4 acc[4] = {};
    const bf16* Abase = Hall + (row0 + lr) * 512 + lk;
    const bf16* Bbase = Wdpk + lr * 512 + lk;
    #pragma unroll
    for (int kk = 0; kk < 16; ++kk) {
        bf16x8 a = *reinterpret_cast<const bf16x8*>(Abase + kk * 32);
        #pragma unroll
        for (int n = 0; n < 4; ++n) {
            bf16x8 b = *reinterpret_cast<const bf16x8*>(Bbase + n * 16 * 512 + kk * 32);
            acc[n] = __builtin_amdgcn_mfma_f32_16x16x32_bf16(a, b, acc[n], 0, 0, 0);
        }
    }
    #pragma unroll
    for (int n = 0; n < 4; ++n) {
        int dcol = n * 16 + lr;
        float bv = bdense[dcol];
        #pragma unroll
        for (int r = 0; r < 4; ++r) {
            long gr = row0 + (lane >> 4) * 4 + r;
            int s = (int)(gr >> 8), b = (int)(gr & 255);
            out[((long)b * 255 + (254 - s)) * 64 + dcol] = acc[n][r] + bv;
        }
    }
}

extern "C" void kernel_launch(void* const* d_in, const int* in_sizes, int n_in,
                              void* d_out, int out_size, void* d_ws, size_t ws_size,
                              hipStream_t stream) {
    const float* enc    = (const float*)d_in[0];
    const float* We0    = (const float*)d_in[2];
    const float* be0    = (const float*)d_in[4];
    const float* We1    = (const float*)d_in[5];
    const float* be1    = (const float*)d_in[7];
    const float* Wd0    = (const float*)d_in[8];
    const float* Ud0    = (const float*)d_in[9];
    const float* bd0    = (const float*)d_in[10];
    const float* Wd1    = (const float*)d_in[11];
    const float* Ud1    = (const float*)d_in[12];
    const float* bd1    = (const float*)d_in[13];
    const float* Wdense = (const float*)d_in[14];
    const float* bdense = (const float*)d_in[15];
    float* out = (float*)d_out;
    char* ws  = (char*)d_ws;

    bf16*  U0     = (bf16*)(ws + OFF_U0);
    bf16*  U1     = (bf16*)(ws + OFF_U1);
    bf16*  We0pk  = (bf16*)(ws + OFF_WE0PK);
    bf16*  We1pk  = (bf16*)(ws + OFF_WE1PK);
    bf16*  Wdpk   = (bf16*)(ws + OFF_WDPK);
    float* be0p   = (float*)(ws + OFF_BE0P);
    float* be1p   = (float*)(ws + OFF_BE1P);
    float* b0f    = (float*)(ws + OFF_B0F);
    float* b1f    = (float*)(ws + OFF_B1F);
    bf16*  A0     = (bf16*)(ws + OFF_A0);
    bf16*  h1     = (bf16*)(ws + OFF_H1);
    float* cbuf   = (float*)(ws + OFF_C);
    bf16*  Hall   = (bf16*)(ws + OFF_HALL);

    // one-time prep (inside graph; ws is re-poisoned every call)
    cast_x    <<<64,   256, 0, stream>>>(enc, A0);
    pack_gatew<<<2048, 256, 0, stream>>>(We0, We0pk, 64);
    pack_gatew<<<2048, 256, 0, stream>>>(We1, We1pk, 512);
    pack_wd   <<<64,   256, 0, stream>>>(Wdense, Wdpk);
    fold_u    <<<2048, 256, 0, stream>>>(Wdense, Wd0, Ud0, U0);
    fold_u    <<<2048, 256, 0, stream>>>(Wdense, Wd1, Ud1, U1);
    prep_bias <<<8,    256, 0, stream>>>(be0, be1, bd0, bd1, bdense, Wd0, Wd1,
                                         be0p, be1p, b0f, b1f);

    dim3 gcell(8, 8);
    // encoder, last timestep only
    cell_kernel<64,  false, false><<<gcell, 256, 0, stream>>>(A0, We0pk, be0p, nullptr, h1);
    cell_kernel<512, false, true ><<<gcell, 256, 0, stream>>>(h1, We1pk, be1p, cbuf, Hall);
    // 254 sequential decoder cells (x folded into Ufold)
    for (int k = 0; k < 254; ++k) {
        cell_kernel<512, true, true><<<gcell, 256, 0, stream>>>(
            Hall + (size_t)k * BH, (k & 1) ? U1 : U0, (k & 1) ? b1f : b0f,
            cbuf, Hall + (size_t)(k + 1) * BH);
    }
    // all 255 outputs in one GEMM (writes every element of d_out)
    y_kernel<<<1020, 256, 0, stream>>>(Hall, Wdpk, bdense, out);
}